// Round 2
// baseline (529.764 us; speedup 1.0000x reference)
//
#include <hip/hip_runtime.h>

#define T_TOK 16384
#define IN_F  1024
#define OUT_F 4096
#define NH    32

// ---------------------------------------------------------------------------
// K1: w_t[h][o] = amp[o][h] * cosf(phase[o][h])  (h-major for K3 staging)
//     + zero res[16384][32] (d_ws is poisoned 0xAA before every call).
// 131072 threads: 1 w element + 1 float4 of res-zero each (131072*4 = 524288).
// ---------------------------------------------------------------------------
__global__ __launch_bounds__(256) void wreal_kernel(
    const float* __restrict__ phase, const float* __restrict__ amp,
    float* __restrict__ w_t, float4* __restrict__ res0)
{
    int idx = blockIdx.x * 256 + threadIdx.x;   // 0 .. 131071
    int o = idx & (OUT_F - 1);
    int h = idx >> 12;
    float p = phase[o * NH + h];
    float a = amp[o * NH + h];
    w_t[h * OUT_F + o] = a * cosf(p);
    res0[idx] = make_float4(0.f, 0.f, 0.f, 0.f);
}

// ---------------------------------------------------------------------------
// K2: res[t][h] += sum_{i in K-slice} x[t][i] * basis[h][i]
// Grid (256 token-tiles, 4 K-slices) = 1024 blocks -> 4 blocks/CU.
// Block: 256 thr, tile 64 tokens x 32 h x 256 K. Thread = 2 tokens x 4 h.
// LDS row stride 68 floats (=4 banks): x reads conflict-free b128; basis
// reads are wave-uniform -> broadcast (free). ~0.5 B LDS per FMA.
// Final: 8 atomicAdds/thread into res (fp32, device-scope).
// ---------------------------------------------------------------------------
#define G1_KC 64
#define KSPLIT 4
#define XS 68

__global__ __launch_bounds__(256) void resonance_kernel(
    const float* __restrict__ x,      // [16384][1024]
    const float* __restrict__ basis,  // [32][1024]
    float* __restrict__ res)          // [16384][32]
{
    __shared__ float xs[64 * XS];     // 17.4 KB
    __shared__ float bs[NH * XS];     // 8.7 KB

    const int tid = threadIdx.x;
    const int t0  = blockIdx.x * 64;
    const int kb  = blockIdx.y;                  // 0..3
    const int ty  = tid & 31;                    // tokens ty, ty+32
    const int th  = tid >> 5;                    // h = 4*th .. 4*th+3

    float acc[2][4] = {};

    for (int kk = 0; kk < IN_F / KSPLIT; kk += G1_KC) {
        const int i0 = kb * (IN_F / KSPLIT) + kk;
        // stage x tile: 64 rows x 16 float4 = 1024 float4 / 256 thr = 4 each
        #pragma unroll
        for (int it = 0; it < 4; ++it) {
            int lin = it * 256 + tid;
            int r = lin >> 4, c = lin & 15;
            float4 v = *(const float4*)(x + (size_t)(t0 + r) * IN_F + i0 + 4 * c);
            *(float4*)(xs + r * XS + 4 * c) = v;
        }
        // stage basis tile: 32 rows x 16 float4 = 512 float4 -> 2 each
        #pragma unroll
        for (int it = 0; it < 2; ++it) {
            int lin = it * 256 + tid;
            int r = lin >> 4, c = lin & 15;
            float4 v = *(const float4*)(basis + (size_t)r * IN_F + i0 + 4 * c);
            *(float4*)(bs + r * XS + 4 * c) = v;
        }
        __syncthreads();

        #pragma unroll
        for (int i = 0; i < G1_KC; i += 4) {
            float4 xa0 = *(const float4*)(xs + ty * XS + i);
            float4 xa1 = *(const float4*)(xs + (ty + 32) * XS + i);
            float4 bb[4];
            #pragma unroll
            for (int j = 0; j < 4; ++j)
                bb[j] = *(const float4*)(bs + (4 * th + j) * XS + i);
            #pragma unroll
            for (int j = 0; j < 4; ++j) {
                acc[0][j] += xa0.x * bb[j].x;
                acc[0][j] += xa0.y * bb[j].y;
                acc[0][j] += xa0.z * bb[j].z;
                acc[0][j] += xa0.w * bb[j].w;
                acc[1][j] += xa1.x * bb[j].x;
                acc[1][j] += xa1.y * bb[j].y;
                acc[1][j] += xa1.z * bb[j].z;
                acc[1][j] += xa1.w * bb[j].w;
            }
        }
        __syncthreads();
    }

    #pragma unroll
    for (int j = 0; j < 4; ++j) {
        atomicAdd(res + (size_t)(t0 + ty) * NH + 4 * th + j, acc[0][j]);
        atomicAdd(res + (size_t)(t0 + ty + 32) * NH + 4 * th + j, acc[1][j]);
    }
}

// ---------------------------------------------------------------------------
// K3: out[t][o] = sum_h res[t][h] * w_t[h][o]
// Zero LDS. Lane owns 4 consecutive outputs: w in 32 float4 VGPRs (loaded
// once). res[t][0..31] is wave-uniform -> scalar loads (s_load_dwordx16 x2
// per token); v_fmac with SGPR src. 2 tokens/iter for s_load-latency ILP.
// Stores: dwordx4, 64 lanes x 16 B = 1 KiB contiguous per wave.
// Grid (4 o-tiles, 256 token-tiles) = 1024 blocks, ~3 blocks/CU @ ~150 VGPR.
// ---------------------------------------------------------------------------
#define TC3 64

__global__ __launch_bounds__(256, 2) void holo_out_kernel(
    const float* __restrict__ res,    // [16384][32]
    const float* __restrict__ w_t,    // [32][4096]
    float* __restrict__ out)          // [16384][4096]
{
    const int tid = threadIdx.x;
    const int o   = blockIdx.x * 1024 + tid * 4;
    const int t0  = blockIdx.y * TC3;

    float4 w4[NH];
    #pragma unroll
    for (int h = 0; h < NH; ++h)
        w4[h] = *(const float4*)(w_t + (size_t)h * OUT_F + o);

    for (int t = t0; t < t0 + TC3; t += 2) {
        const float* r0 = res + (size_t)t * NH;        // wave-uniform address
        const float* r1 = r0 + NH;
        float4 a0 = make_float4(0.f, 0.f, 0.f, 0.f);
        float4 a1 = make_float4(0.f, 0.f, 0.f, 0.f);
        #pragma unroll
        for (int h = 0; h < NH; ++h) {
            float s0 = r0[h];
            float s1 = r1[h];
            a0.x += s0 * w4[h].x; a0.y += s0 * w4[h].y;
            a0.z += s0 * w4[h].z; a0.w += s0 * w4[h].w;
            a1.x += s1 * w4[h].x; a1.y += s1 * w4[h].y;
            a1.z += s1 * w4[h].z; a1.w += s1 * w4[h].w;
        }
        *(float4*)(out + (size_t)t * OUT_F + o)       = a0;
        *(float4*)(out + (size_t)(t + 1) * OUT_F + o) = a1;
    }
}

// ---------------------------------------------------------------------------
extern "C" void kernel_launch(void* const* d_in, const int* in_sizes, int n_in,
                              void* d_out, int out_size, void* d_ws, size_t ws_size,
                              hipStream_t stream)
{
    const float* x     = (const float*)d_in[0];  // [16384,1024]
    const float* basis = (const float*)d_in[1];  // [32,1024]
    const float* phase = (const float*)d_in[2];  // [4096,32]
    const float* amp   = (const float*)d_in[3];  // [4096,32]
    float* out = (float*)d_out;                  // [16384,4096] fp32

    float* res = (float*)d_ws;                        // 16384*32 floats = 2 MB
    float* w_t = res + (size_t)T_TOK * NH;            // 32*4096 floats = 512 KB

    wreal_kernel<<<dim3((OUT_F * NH) / 256), dim3(256), 0, stream>>>(
        phase, amp, w_t, (float4*)res);
    resonance_kernel<<<dim3(T_TOK / 64, KSPLIT), dim3(256), 0, stream>>>(
        x, basis, res);
    holo_out_kernel<<<dim3(OUT_F / 1024, T_TOK / TC3), dim3(256), 0, stream>>>(
        res, w_t, out);
}